// Round 1
// baseline (218.710 us; speedup 1.0000x reference)
//
#include <hip/hip_runtime.h>
#include <math.h>

// TrackCrossAttention: B=2, C=4096, D_MODEL=512, H=8, d_head=64, T=16, d_track=64
// Chain (all through buf = d_out, in-place per token row):
//   k1: x -> Q                      (RMSNorm + Q GEMM, 16 tok/block)
//   k2: Q -> qw   qw[h,d]=sum_e Q[h,e]*wk[d,h*64+e]     (per-head 64x64)
//   k3: qw,track -> wtf  (logits, softmax, wtf[h,d]=sum_t w[h,t]*tf[t,d])
//   k4: wtf -> attn_out  ao[h*64+e]=sum_d wtf[h,d]*wv[d,h*64+e]+bv
//   k5: attn_out -> out = x + ao@wo + bo

#define NTOKTOT 8192

__global__ __launch_bounds__(256) void k1_rmsnorm_q(
    const float* __restrict__ x, const float* __restrict__ nscale,
    const float* __restrict__ wq, const float* __restrict__ bq,
    float* __restrict__ buf)
{
    __shared__ float xn[16][512];
    const int tid = threadIdx.x;
    const int tok0 = blockIdx.x * 16;
    {
        const int tt = tid >> 4;
        const int p  = tid & 15;
        const float* xr = x + (size_t)(tok0 + tt) * 512;
        float4 xv[8];
        float s = 0.f;
        #pragma unroll
        for (int i = 0; i < 8; ++i) {
            xv[i] = *reinterpret_cast<const float4*>(xr + (p + 16*i)*4);
            s += xv[i].x*xv[i].x + xv[i].y*xv[i].y + xv[i].z*xv[i].z + xv[i].w*xv[i].w;
        }
        #pragma unroll
        for (int m = 1; m < 16; m <<= 1) s += __shfl_xor(s, m, 64);
        const float r = rsqrtf(s * (1.f/512.f) + 1e-6f);
        #pragma unroll
        for (int i = 0; i < 8; ++i) {
            const float4 sc = *reinterpret_cast<const float4*>(nscale + (p + 16*i)*4);
            float4 v;
            v.x = xv[i].x * r * sc.x;
            v.y = xv[i].y * r * sc.y;
            v.z = xv[i].z * r * sc.z;
            v.w = xv[i].w * r * sc.w;
            *reinterpret_cast<float4*>(&xn[tt][(p + 16*i)*4]) = v;
        }
    }
    __syncthreads();
    const int tx = tid & 63;
    const int ty = tid >> 6;
    float acc[4][8];
    #pragma unroll
    for (int m = 0; m < 4; ++m)
        #pragma unroll
        for (int n = 0; n < 8; ++n) acc[m][n] = 0.f;
    for (int d0 = 0; d0 < 512; d0 += 4) {
        float4 a[4];
        #pragma unroll
        for (int m = 0; m < 4; ++m)
            a[m] = *reinterpret_cast<const float4*>(&xn[ty*4 + m][d0]);
        #pragma unroll
        for (int dd = 0; dd < 4; ++dd) {
            const float4 b0 = *reinterpret_cast<const float4*>(wq + (size_t)(d0+dd)*512 + tx*8);
            const float4 b1 = *reinterpret_cast<const float4*>(wq + (size_t)(d0+dd)*512 + tx*8 + 4);
            #pragma unroll
            for (int m = 0; m < 4; ++m) {
                const float am = reinterpret_cast<const float*>(&a[m])[dd];
                acc[m][0] += am*b0.x; acc[m][1] += am*b0.y;
                acc[m][2] += am*b0.z; acc[m][3] += am*b0.w;
                acc[m][4] += am*b1.x; acc[m][5] += am*b1.y;
                acc[m][6] += am*b1.z; acc[m][7] += am*b1.w;
            }
        }
    }
    const float4 q0 = *reinterpret_cast<const float4*>(bq + tx*8);
    const float4 q1 = *reinterpret_cast<const float4*>(bq + tx*8 + 4);
    #pragma unroll
    for (int m = 0; m < 4; ++m) {
        float* orow = buf + (size_t)(tok0 + ty*4 + m) * 512 + tx*8;
        float4 o0, o1;
        o0.x = acc[m][0]+q0.x; o0.y = acc[m][1]+q0.y;
        o0.z = acc[m][2]+q0.z; o0.w = acc[m][3]+q0.w;
        o1.x = acc[m][4]+q1.x; o1.y = acc[m][5]+q1.y;
        o1.z = acc[m][6]+q1.z; o1.w = acc[m][7]+q1.w;
        *reinterpret_cast<float4*>(orow)     = o0;
        *reinterpret_cast<float4*>(orow + 4) = o1;
    }
}

__global__ __launch_bounds__(256) void k2_qw(
    const float* __restrict__ wk, float* __restrict__ buf)
{
    __shared__ float qld[16][512];
    __shared__ float wkh[64][65];
    const int tid = threadIdx.x;
    const int tok0 = blockIdx.x * 16;
    #pragma unroll
    for (int i = 0; i < 8; ++i) {
        const int f4 = tid + i*256;     // 0..2047, 128 float4 per row
        const int row = f4 >> 7;
        const int c4 = f4 & 127;
        *reinterpret_cast<float4*>(&qld[row][c4*4]) =
            *reinterpret_cast<const float4*>(buf + (size_t)(tok0+row)*512 + c4*4);
    }
    for (int h = 0; h < 8; ++h) {
        __syncthreads();
        #pragma unroll
        for (int i = 0; i < 16; ++i) {
            const int idx = tid + i*256;   // 0..4095
            const int d = idx >> 6, e = idx & 63;
            wkh[d][e] = wk[(size_t)d*512 + h*64 + e];
        }
        __syncthreads();
        const int d = tid & 63;
        const int tg = tid >> 6;
        #pragma unroll
        for (int pass = 0; pass < 4; ++pass) {
            const int tok = tg + pass*4;
            float acc = 0.f;
            #pragma unroll
            for (int e = 0; e < 64; ++e)
                acc += qld[tok][h*64 + e] * wkh[d][e];
            buf[(size_t)(tok0 + tok)*512 + h*64 + d] = acc;
        }
    }
}

__global__ __launch_bounds__(256) void k3_attn(
    const float* __restrict__ track, float* __restrict__ buf)
{
    __shared__ float tf[16][68];
    __shared__ float qwl[8][68];
    __shared__ float lw[8][16];
    const int tid = threadIdx.x;
    const int token = blockIdx.x;
    const int b = token >> 12;     // C = 4096
    const int c = token & 4095;
    {
        const int t = tid >> 4;
        const int d4 = (tid & 15) * 4;
        *reinterpret_cast<float4*>(&tf[t][d4]) =
            *reinterpret_cast<const float4*>(track + ((size_t)(b*16 + t)*4096 + c)*64 + d4);
    }
    if (tid < 128) {
        const int h = tid >> 4;
        const int d4 = (tid & 15) * 4;
        *reinterpret_cast<float4*>(&qwl[h][d4]) =
            *reinterpret_cast<const float4*>(buf + (size_t)token*512 + h*64 + d4);
    }
    __syncthreads();
    if (tid < 128) {
        const int h = tid >> 4, t = tid & 15;
        float acc = 0.f;
        #pragma unroll
        for (int d = 0; d < 64; ++d) acc += qwl[h][d] * tf[t][d];
        lw[h][t] = acc * 0.125f;   // 1/sqrt(64)
    }
    __syncthreads();
    if (tid < 8) {
        float mx = -1e30f;
        #pragma unroll
        for (int t = 0; t < 16; ++t) mx = fmaxf(mx, lw[tid][t]);
        float ev[16];
        float sum = 0.f;
        #pragma unroll
        for (int t = 0; t < 16; ++t) { ev[t] = expf(lw[tid][t] - mx); sum += ev[t]; }
        const float inv = 1.f / sum;
        #pragma unroll
        for (int t = 0; t < 16; ++t) lw[tid][t] = ev[t] * inv;
    }
    __syncthreads();
    #pragma unroll
    for (int pass = 0; pass < 2; ++pass) {
        const int j = tid + pass*256;
        const int h = j >> 6, d = j & 63;
        float acc = 0.f;
        #pragma unroll
        for (int t = 0; t < 16; ++t) acc += lw[h][t] * tf[t][d];
        buf[(size_t)token*512 + j] = acc;
    }
}

__global__ __launch_bounds__(256) void k4_av(
    const float* __restrict__ wv, const float* __restrict__ bv,
    float* __restrict__ buf)
{
    __shared__ float wl[16][512];
    __shared__ float wvh[64][65];
    const int tid = threadIdx.x;
    const int tok0 = blockIdx.x * 16;
    #pragma unroll
    for (int i = 0; i < 8; ++i) {
        const int f4 = tid + i*256;
        const int row = f4 >> 7;
        const int c4 = f4 & 127;
        *reinterpret_cast<float4*>(&wl[row][c4*4]) =
            *reinterpret_cast<const float4*>(buf + (size_t)(tok0+row)*512 + c4*4);
    }
    for (int h = 0; h < 8; ++h) {
        __syncthreads();
        #pragma unroll
        for (int i = 0; i < 16; ++i) {
            const int idx = tid + i*256;
            const int d = idx >> 6, e = idx & 63;
            wvh[d][e] = wv[(size_t)d*512 + h*64 + e];
        }
        __syncthreads();
        const int e = tid & 63;
        const int tg = tid >> 6;
        const float bve = bv[h*64 + e];
        #pragma unroll
        for (int pass = 0; pass < 4; ++pass) {
            const int tok = tg + pass*4;
            float acc = bve;
            #pragma unroll
            for (int d = 0; d < 64; ++d)
                acc += wl[tok][h*64 + d] * wvh[d][e];
            buf[(size_t)(tok0 + tok)*512 + h*64 + e] = acc;
        }
    }
}

__global__ __launch_bounds__(256) void k5_out(
    const float* __restrict__ x, const float* __restrict__ wo,
    const float* __restrict__ bo, float* __restrict__ buf)
{
    __shared__ float ao[16][512];
    const int tid = threadIdx.x;
    const int tok0 = blockIdx.x * 16;
    #pragma unroll
    for (int i = 0; i < 8; ++i) {
        const int f4 = tid + i*256;
        const int row = f4 >> 7;
        const int c4 = f4 & 127;
        *reinterpret_cast<float4*>(&ao[row][c4*4]) =
            *reinterpret_cast<const float4*>(buf + (size_t)(tok0+row)*512 + c4*4);
    }
    __syncthreads();
    const int tx = tid & 63;
    const int ty = tid >> 6;
    float acc[4][8];
    #pragma unroll
    for (int m = 0; m < 4; ++m)
        #pragma unroll
        for (int n = 0; n < 8; ++n) acc[m][n] = 0.f;
    for (int d0 = 0; d0 < 512; d0 += 4) {
        float4 a[4];
        #pragma unroll
        for (int m = 0; m < 4; ++m)
            a[m] = *reinterpret_cast<const float4*>(&ao[ty*4 + m][d0]);
        #pragma unroll
        for (int dd = 0; dd < 4; ++dd) {
            const float4 b0 = *reinterpret_cast<const float4*>(wo + (size_t)(d0+dd)*512 + tx*8);
            const float4 b1 = *reinterpret_cast<const float4*>(wo + (size_t)(d0+dd)*512 + tx*8 + 4);
            #pragma unroll
            for (int m = 0; m < 4; ++m) {
                const float am = reinterpret_cast<const float*>(&a[m])[dd];
                acc[m][0] += am*b0.x; acc[m][1] += am*b0.y;
                acc[m][2] += am*b0.z; acc[m][3] += am*b0.w;
                acc[m][4] += am*b1.x; acc[m][5] += am*b1.y;
                acc[m][6] += am*b1.z; acc[m][7] += am*b1.w;
            }
        }
    }
    const float4 c0 = *reinterpret_cast<const float4*>(bo + tx*8);
    const float4 c1 = *reinterpret_cast<const float4*>(bo + tx*8 + 4);
    #pragma unroll
    for (int m = 0; m < 4; ++m) {
        const size_t roff = (size_t)(tok0 + ty*4 + m) * 512 + tx*8;
        const float4 r0 = *reinterpret_cast<const float4*>(x + roff);
        const float4 r1 = *reinterpret_cast<const float4*>(x + roff + 4);
        float4 o0, o1;
        o0.x = acc[m][0]+c0.x+r0.x; o0.y = acc[m][1]+c0.y+r0.y;
        o0.z = acc[m][2]+c0.z+r0.z; o0.w = acc[m][3]+c0.w+r0.w;
        o1.x = acc[m][4]+c1.x+r1.x; o1.y = acc[m][5]+c1.y+r1.y;
        o1.z = acc[m][6]+c1.z+r1.z; o1.w = acc[m][7]+c1.w+r1.w;
        *reinterpret_cast<float4*>(buf + roff)     = o0;
        *reinterpret_cast<float4*>(buf + roff + 4) = o1;
    }
}

extern "C" void kernel_launch(void* const* d_in, const int* in_sizes, int n_in,
                              void* d_out, int out_size, void* d_ws, size_t ws_size,
                              hipStream_t stream) {
    const float* x      = (const float*)d_in[0];
    const float* track  = (const float*)d_in[1];
    const float* nscale = (const float*)d_in[2];
    const float* wq     = (const float*)d_in[3];
    const float* bq     = (const float*)d_in[4];
    const float* wk     = (const float*)d_in[5];
    // d_in[6] = bk: constant over t per head -> softmax-invariant, omitted exactly
    const float* wv     = (const float*)d_in[7];
    const float* bv     = (const float*)d_in[8];
    const float* wo     = (const float*)d_in[9];
    const float* bo     = (const float*)d_in[10];
    float* buf = (float*)d_out;

    k1_rmsnorm_q<<<NTOKTOT/16, 256, 0, stream>>>(x, nscale, wq, bq, buf);
    k2_qw<<<NTOKTOT/16, 256, 0, stream>>>(wk, buf);
    k3_attn<<<NTOKTOT, 256, 0, stream>>>(track, buf);
    k4_av<<<NTOKTOT/16, 256, 0, stream>>>(wv, bv, buf);
    k5_out<<<NTOKTOT/16, 256, 0, stream>>>(x, wo, bo, buf);
}

// Round 2
// 88.972 us; speedup vs baseline: 2.4582x; 2.4582x over previous
//
#include <hip/hip_runtime.h>
#include <math.h>

// TrackCrossAttention, algebraically restructured:
//   wqkT[j=h*64+d][i] = sum_e wq[i][h*64+e]*wk[d][h*64+e]   (bf16, transposed)
//   bqk[h*64+d]       = sum_e bq[h*64+e]*wk[d][h*64+e]
//   wvoT[j][h*64+d]   = sum_e wv[d][h*64+e]*wo[h*64+e][j]   (bf16, transposed)
//   bvo[j]            = sum_e bv[e]*wo[e][j] + bo[j]
// Pipeline:
//   kA : RMSNorm(x) -> xn bf16 (ws)
//   kG1: qw = xn @ wqk + bqk -> buf (f32)        [MFMA]
//   k3 : logits/softmax/wtf -> wtf bf16 (ws)
//   kG2: out = x + wtf @ wvo + bvo -> buf (f32)  [MFMA]

#define NTOK 8192

typedef __attribute__((ext_vector_type(8))) short short8;
typedef __attribute__((ext_vector_type(8))) unsigned short ushort8;
typedef __attribute__((ext_vector_type(4))) float f32x4;

__device__ __forceinline__ unsigned short f2bf(float f) {
    unsigned int u = __float_as_uint(f);
    unsigned int r = (u + 0x7fffu + ((u >> 16) & 1u)) >> 16;
    return (unsigned short)r;
}

__device__ __forceinline__ void gl_lds16(const void* g, void* l) {
    __builtin_amdgcn_global_load_lds(
        (const __attribute__((address_space(1))) unsigned int*)g,
        (__attribute__((address_space(3))) unsigned int*)l,
        16, 0, 0);
}

// ---------------- weight precompute ----------------

__global__ __launch_bounds__(256) void kprec1(
    const float* __restrict__ wq, const float* __restrict__ bq,
    const float* __restrict__ wk,
    unsigned short* __restrict__ wqkT, float* __restrict__ bqk)
{
    __shared__ float wkL[64][65];
    __shared__ float wqL[64][65];
    const int t = threadIdx.x;
    const int h = blockIdx.x >> 3;
    const int i0 = (blockIdx.x & 7) * 64;
    #pragma unroll
    for (int i = 0; i < 16; ++i) {
        const int idx = t + i * 256;
        const int d = idx >> 6, e = idx & 63;
        wkL[d][e] = wk[(size_t)d * 512 + h * 64 + e];
        wqL[d][e] = wq[(size_t)(i0 + d) * 512 + h * 64 + e];
    }
    __syncthreads();
    const int d = t & 63, ig = t >> 6;
    float acc[16];
    #pragma unroll
    for (int ii = 0; ii < 16; ++ii) acc[ii] = 0.f;
    for (int e = 0; e < 64; ++e) {
        const float kv = wkL[d][e];
        #pragma unroll
        for (int ii = 0; ii < 16; ++ii)
            acc[ii] += kv * wqL[ig * 16 + ii][e];
    }
    #pragma unroll
    for (int ii = 0; ii < 16; ++ii)
        wqkT[(size_t)(h * 64 + d) * 512 + i0 + ig * 16 + ii] = f2bf(acc[ii]);
    if (((blockIdx.x & 7) == 0) && ig == 0) {
        float a = 0.f;
        #pragma unroll
        for (int e = 0; e < 64; ++e) a += bq[h * 64 + e] * wkL[d][e];
        bqk[h * 64 + d] = a;
    }
}

__global__ __launch_bounds__(256) void kprec2(
    const float* __restrict__ wv, const float* __restrict__ wo,
    unsigned short* __restrict__ wvoT)
{
    __shared__ float wvL[64][65];   // [d][e]
    __shared__ float woL[64][65];   // [e][jloc]
    const int t = threadIdx.x;
    const int h = blockIdx.x >> 3;
    const int j0 = (blockIdx.x & 7) * 64;
    #pragma unroll
    for (int i = 0; i < 16; ++i) {
        const int idx = t + i * 256;
        const int a = idx >> 6, b = idx & 63;
        wvL[a][b] = wv[(size_t)a * 512 + h * 64 + b];
        woL[a][b] = wo[(size_t)(h * 64 + a) * 512 + j0 + b];
    }
    __syncthreads();
    const int jloc = t & 63, dg = t >> 6;
    float acc[16];
    #pragma unroll
    for (int dd = 0; dd < 16; ++dd) acc[dd] = 0.f;
    for (int e = 0; e < 64; ++e) {
        const float b = woL[e][jloc];
        #pragma unroll
        for (int dd = 0; dd < 16; ++dd)
            acc[dd] += wvL[dg * 16 + dd][e] * b;
    }
    #pragma unroll
    for (int dd = 0; dd < 16; ++dd)
        wvoT[(size_t)(j0 + jloc) * 512 + h * 64 + dg * 16 + dd] = f2bf(acc[dd]);
}

__global__ __launch_bounds__(256) void kprec3(
    const float* __restrict__ bv, const float* __restrict__ wo,
    const float* __restrict__ bo, float* __restrict__ bvo)
{
    const int j = blockIdx.x * 256 + threadIdx.x;
    float a = bo[j];
    for (int e = 0; e < 512; ++e) a += bv[e] * wo[(size_t)e * 512 + j];
    bvo[j] = a;
}

// ---------------- RMSNorm -> bf16 ----------------

__global__ __launch_bounds__(256) void kA(
    const float* __restrict__ x, const float* __restrict__ nscale,
    unsigned short* __restrict__ xnb)
{
    const int row = blockIdx.x * 4 + (threadIdx.x >> 6);
    const int lane = threadIdx.x & 63;
    const float* xr = x + (size_t)row * 512 + lane * 8;
    const float4 v0 = *reinterpret_cast<const float4*>(xr);
    const float4 v1 = *reinterpret_cast<const float4*>(xr + 4);
    float s = v0.x*v0.x + v0.y*v0.y + v0.z*v0.z + v0.w*v0.w
            + v1.x*v1.x + v1.y*v1.y + v1.z*v1.z + v1.w*v1.w;
    #pragma unroll
    for (int m = 1; m < 64; m <<= 1) s += __shfl_xor(s, m, 64);
    const float r = rsqrtf(s * (1.f / 512.f) + 1e-6f);
    const float4 s0 = *reinterpret_cast<const float4*>(nscale + lane * 8);
    const float4 s1 = *reinterpret_cast<const float4*>(nscale + lane * 8 + 4);
    ushort8 o;
    o[0] = f2bf(v0.x * r * s0.x); o[1] = f2bf(v0.y * r * s0.y);
    o[2] = f2bf(v0.z * r * s0.z); o[3] = f2bf(v0.w * r * s0.w);
    o[4] = f2bf(v1.x * r * s1.x); o[5] = f2bf(v1.y * r * s1.y);
    o[6] = f2bf(v1.z * r * s1.z); o[7] = f2bf(v1.w * r * s1.w);
    *reinterpret_cast<ushort8*>(xnb + (size_t)row * 512 + lane * 8) = o;
}

// ---------------- MFMA GEMM: [8192x512] x [512x512] ----------------
// A row-major bf16, Bt = B transposed [N][K] bf16, out f32 (+bias, +resid)

template<bool RESID>
__global__ __launch_bounds__(256) void kG(
    const unsigned short* __restrict__ A,
    const unsigned short* __restrict__ Bt,
    const float* __restrict__ bias,
    const float* __restrict__ resid,
    float* __restrict__ out)
{
    __shared__ __align__(16) unsigned short Asm[128 * 64];
    __shared__ __align__(16) unsigned short Bsm[64 * 64];
    const int tid = threadIdx.x;
    const int mt = blockIdx.x >> 3, nt = blockIdx.x & 7;
    const int tok0 = mt * 128, n0 = nt * 64;
    const int w = tid >> 6, lane = tid & 63;
    const int wr = w >> 1, wc = w & 1;
    const int lrow = lane & 15, lk = lane >> 4;

    f32x4 acc[4][2] = {};
    for (int k0 = 0; k0 < 512; k0 += 64) {
        #pragma unroll
        for (int i = 0; i < 4; ++i) {
            const int f = tid + i * 256;          // 0..1023
            const int row = f >> 3, c8 = f & 7;
            const int c8s = c8 ^ (row & 7);       // pre-swizzled source
            gl_lds16(A + (size_t)(tok0 + row) * 512 + k0 + c8s * 8,
                     (char*)Asm + f * 16);
        }
        #pragma unroll
        for (int i = 0; i < 2; ++i) {
            const int f = tid + i * 256;          // 0..511
            const int row = f >> 3, c8 = f & 7;
            const int c8s = c8 ^ (row & 7);
            gl_lds16(Bt + (size_t)(n0 + row) * 512 + k0 + c8s * 8,
                     (char*)Bsm + f * 16);
        }
        __syncthreads();   // drains vmcnt before barrier (compiler-inserted)
        #pragma unroll
        for (int kk = 0; kk < 2; ++kk) {
            short8 a[4], b[2];
            #pragma unroll
            for (int m = 0; m < 4; ++m) {
                const int r = wr * 64 + m * 16 + lrow;
                const int byte = (r * 128 + kk * 64 + lk * 16) ^ ((r & 7) << 4);
                a[m] = *reinterpret_cast<const short8*>((const char*)Asm + byte);
            }
            #pragma unroll
            for (int n = 0; n < 2; ++n) {
                const int r = wc * 32 + n * 16 + lrow;
                const int byte = (r * 128 + kk * 64 + lk * 16) ^ ((r & 7) << 4);
                b[n] = *reinterpret_cast<const short8*>((const char*)Bsm + byte);
            }
            #pragma unroll
            for (int m = 0; m < 4; ++m)
                #pragma unroll
                for (int n = 0; n < 2; ++n)
                    acc[m][n] = __builtin_amdgcn_mfma_f32_16x16x32_bf16(
                        a[m], b[n], acc[m][n], 0, 0, 0);
        }
        __syncthreads();
    }
    #pragma unroll
    for (int n = 0; n < 2; ++n) {
        const int ocol = n0 + wc * 32 + n * 16 + lrow;
        const float bs = bias[ocol];
        #pragma unroll
        for (int m = 0; m < 4; ++m) {
            #pragma unroll
            for (int r = 0; r < 4; ++r) {
                const int orow = tok0 + wr * 64 + m * 16 + lk * 4 + r;
                float v = acc[m][n][r] + bs;
                if (RESID) v += resid[(size_t)orow * 512 + ocol];
                out[(size_t)orow * 512 + ocol] = v;
            }
        }
    }
}

// ---------------- attention core ----------------

__global__ __launch_bounds__(256) void k3_attn(
    const float* __restrict__ track, const float* __restrict__ qwbuf,
    unsigned short* __restrict__ wtfb)
{
    __shared__ float tf[16][68];
    __shared__ float qwl[8][68];
    __shared__ float lw[8][16];
    const int tid = threadIdx.x;
    const int token = blockIdx.x;
    const int b = token >> 12;
    const int c = token & 4095;
    {
        const int t = tid >> 4;
        const int d4 = (tid & 15) * 4;
        *reinterpret_cast<float4*>(&tf[t][d4]) =
            *reinterpret_cast<const float4*>(track + ((size_t)(b * 16 + t) * 4096 + c) * 64 + d4);
    }
    if (tid < 128) {
        const int h = tid >> 4;
        const int d4 = (tid & 15) * 4;
        *reinterpret_cast<float4*>(&qwl[h][d4]) =
            *reinterpret_cast<const float4*>(qwbuf + (size_t)token * 512 + h * 64 + d4);
    }
    __syncthreads();
    if (tid < 128) {
        const int h = tid >> 4, t = tid & 15;
        float acc = 0.f;
        #pragma unroll
        for (int d = 0; d < 64; ++d) acc += qwl[h][d] * tf[t][d];
        lw[h][t] = acc * 0.125f;
    }
    __syncthreads();
    if (tid < 8) {
        float mx = -1e30f;
        #pragma unroll
        for (int t = 0; t < 16; ++t) mx = fmaxf(mx, lw[tid][t]);
        float ev[16];
        float sum = 0.f;
        #pragma unroll
        for (int t = 0; t < 16; ++t) { ev[t] = expf(lw[tid][t] - mx); sum += ev[t]; }
        const float inv = 1.f / sum;
        #pragma unroll
        for (int t = 0; t < 16; ++t) lw[tid][t] = ev[t] * inv;
    }
    __syncthreads();
    #pragma unroll
    for (int pass = 0; pass < 2; ++pass) {
        const int j = tid + pass * 256;
        const int h = j >> 6, d = j & 63;
        float acc = 0.f;
        #pragma unroll
        for (int t = 0; t < 16; ++t) acc += lw[h][t] * tf[t][d];
        wtfb[(size_t)token * 512 + j] = f2bf(acc);
    }
}

extern "C" void kernel_launch(void* const* d_in, const int* in_sizes, int n_in,
                              void* d_out, int out_size, void* d_ws, size_t ws_size,
                              hipStream_t stream) {
    const float* x      = (const float*)d_in[0];
    const float* track  = (const float*)d_in[1];
    const float* nscale = (const float*)d_in[2];
    const float* wq     = (const float*)d_in[3];
    const float* bq     = (const float*)d_in[4];
    const float* wk     = (const float*)d_in[5];
    // d_in[6] = bk: constant over t per head -> softmax-invariant, omitted exactly
    const float* wv     = (const float*)d_in[7];
    const float* bv     = (const float*)d_in[8];
    const float* wo     = (const float*)d_in[9];
    const float* bo     = (const float*)d_in[10];
    float* buf = (float*)d_out;

    char* ws = (char*)d_ws;
    unsigned short* xnb  = (unsigned short*)ws;               // 8 MB (xn, later wtf)
    unsigned short* wqkT = (unsigned short*)(ws + 8388608);   // 512 KB
    unsigned short* wvoT = (unsigned short*)(ws + 8912896);   // 512 KB
    float* bqk = (float*)(ws + 9437184);                      // 2 KB
    float* bvo = (float*)(ws + 9439232);                      // 2 KB

    kprec1<<<64, 256, 0, stream>>>(wq, bq, wk, wqkT, bqk);
    kprec2<<<64, 256, 0, stream>>>(wv, wo, wvoT);
    kprec3<<<2, 256, 0, stream>>>(bv, wo, bo, bvo);
    kA<<<NTOK / 4, 256, 0, stream>>>(x, nscale, xnb);
    kG<false><<<512, 256, 0, stream>>>(xnb, wqkT, bqk, nullptr, buf);
    k3_attn<<<NTOK, 256, 0, stream>>>(track, buf, xnb);       // xn dead, reuse as wtf
    kG<true><<<512, 256, 0, stream>>>(xnb, wvoT, bvo, x, buf);
}

// Round 3
// 58.771 us; speedup vs baseline: 3.7214x; 1.5139x over previous
//
#include <hip/hip_runtime.h>
#include <math.h>

// TrackCrossAttention, algebraically restructured:
//   wqkT[j=h*64+d][i] = sum_e wq[i][h*64+e]*wk[d][h*64+e]   (bf16, transposed)
//   bqk[h*64+d]       = sum_e bq[h*64+e]*wk[d][h*64+e]
//   wvoT[j][h*64+d]   = sum_e wv[d][h*64+e]*wo[h*64+e][j]   (bf16, transposed)
//   bvo[j]            = sum_e bv[e]*wo[e][j] + bo[j]
// Pipeline (4 kernels):
//   kprep: [bid<64] wqkT/bqk  [64..127] wvoT  [128..191] bvo  [192+] RMSNorm->xn bf16
//   kG<0>: qw = xn @ wqk + bqk -> bf16 (ws)      [MFMA]
//   k3   : logits/softmax/wtf -> wtf bf16 (ws)
//   kG<1>: out = x + wtf @ wvo + bvo -> f32 buf  [MFMA]

#define NTOK 8192

typedef __attribute__((ext_vector_type(8))) short short8;
typedef __attribute__((ext_vector_type(8))) unsigned short ushort8;
typedef __attribute__((ext_vector_type(4))) unsigned short ushort4v;
typedef __attribute__((ext_vector_type(4))) float f32x4;

__device__ __forceinline__ unsigned short f2bf(float f) {
    unsigned int u = __float_as_uint(f);
    unsigned int r = (u + 0x7fffu + ((u >> 16) & 1u)) >> 16;
    return (unsigned short)r;
}
__device__ __forceinline__ float bf2f(unsigned short s) {
    return __uint_as_float(((unsigned int)s) << 16);
}

__device__ __forceinline__ void gl_lds16(const void* g, void* l) {
    __builtin_amdgcn_global_load_lds(
        (const __attribute__((address_space(1))) unsigned int*)g,
        (__attribute__((address_space(3))) unsigned int*)l,
        16, 0, 0);
}

// ---------------- fused prep: weight folding + RMSNorm ----------------

__global__ __launch_bounds__(256) void kprep(
    const float* __restrict__ x, const float* __restrict__ nscale,
    const float* __restrict__ wq, const float* __restrict__ bq,
    const float* __restrict__ wk, const float* __restrict__ wv,
    const float* __restrict__ bv, const float* __restrict__ wo,
    const float* __restrict__ bo,
    unsigned short* __restrict__ wqkT, float* __restrict__ bqk,
    unsigned short* __restrict__ wvoT, float* __restrict__ bvo,
    unsigned short* __restrict__ xnb)
{
    const int bid = blockIdx.x;
    const int t = threadIdx.x;
    if (bid < 64) {
        // wqkT[h*64+d][i] = sum_e wq[i][h*64+e]*wk[d][h*64+e]
        __shared__ float wkL[64][65];
        __shared__ float wqL[64][65];
        const int h = bid >> 3;
        const int i0 = (bid & 7) * 64;
        #pragma unroll
        for (int i = 0; i < 16; ++i) {
            const int idx = t + i * 256;
            const int d = idx >> 6, e = idx & 63;
            wkL[d][e] = wk[(size_t)d * 512 + h * 64 + e];
            wqL[d][e] = wq[(size_t)(i0 + d) * 512 + h * 64 + e];
        }
        __syncthreads();
        const int d = t & 63, ig = t >> 6;
        float acc[16];
        #pragma unroll
        for (int ii = 0; ii < 16; ++ii) acc[ii] = 0.f;
        for (int e = 0; e < 64; ++e) {
            const float kv = wkL[d][e];
            #pragma unroll
            for (int ii = 0; ii < 16; ++ii)
                acc[ii] += kv * wqL[ig * 16 + ii][e];
        }
        #pragma unroll
        for (int ii = 0; ii < 16; ++ii)
            wqkT[(size_t)(h * 64 + d) * 512 + i0 + ig * 16 + ii] = f2bf(acc[ii]);
        if (((bid & 7) == 0) && ig == 0) {
            float a = 0.f;
            #pragma unroll
            for (int e = 0; e < 64; ++e) a += bq[h * 64 + e] * wkL[d][e];
            bqk[h * 64 + d] = a;
        }
    } else if (bid < 128) {
        // wvoT[j][h*64+d] = sum_e wv[d][h*64+e]*wo[h*64+e][j]
        __shared__ float wvL[64][65];   // [d][e]
        __shared__ float woL[64][65];   // [e][jloc]
        const int b2 = bid - 64;
        const int h = b2 >> 3;
        const int j0 = (b2 & 7) * 64;
        #pragma unroll
        for (int i = 0; i < 16; ++i) {
            const int idx = t + i * 256;
            const int a = idx >> 6, b = idx & 63;
            wvL[a][b] = wv[(size_t)a * 512 + h * 64 + b];
            woL[a][b] = wo[(size_t)(h * 64 + a) * 512 + j0 + b];
        }
        __syncthreads();
        const int jloc = t & 63, dg = t >> 6;
        float acc[16];
        #pragma unroll
        for (int dd = 0; dd < 16; ++dd) acc[dd] = 0.f;
        for (int e = 0; e < 64; ++e) {
            const float b = woL[e][jloc];
            #pragma unroll
            for (int dd = 0; dd < 16; ++dd)
                acc[dd] += wvL[dg * 16 + dd][e] * b;
        }
        #pragma unroll
        for (int dd = 0; dd < 16; ++dd)
            wvoT[(size_t)(j0 + jloc) * 512 + h * 64 + dg * 16 + dd] = f2bf(acc[dd]);
    } else if (bid < 192) {
        // bvo[j] = bo[j] + sum_e bv[e]*wo[e*512+j] ; 8 j per block, 32 lanes per j
        const int b3 = bid - 128;
        const int j = b3 * 8 + (t >> 5);
        const int l = t & 31;
        float p = 0.f;
        #pragma unroll 4
        for (int e = l; e < 512; e += 32) p += bv[e] * wo[(size_t)e * 512 + j];
        #pragma unroll
        for (int m = 1; m < 32; m <<= 1) p += __shfl_xor(p, m, 64);
        if (l == 0) bvo[j] = bo[j] + p;
    } else {
        // RMSNorm -> bf16, 4 rows/block
        const int row = (bid - 192) * 4 + (t >> 6);
        const int lane = t & 63;
        const float* xr = x + (size_t)row * 512 + lane * 8;
        const float4 v0 = *reinterpret_cast<const float4*>(xr);
        const float4 v1 = *reinterpret_cast<const float4*>(xr + 4);
        float s = v0.x*v0.x + v0.y*v0.y + v0.z*v0.z + v0.w*v0.w
                + v1.x*v1.x + v1.y*v1.y + v1.z*v1.z + v1.w*v1.w;
        #pragma unroll
        for (int m = 1; m < 64; m <<= 1) s += __shfl_xor(s, m, 64);
        const float r = rsqrtf(s * (1.f / 512.f) + 1e-6f);
        const float4 s0 = *reinterpret_cast<const float4*>(nscale + lane * 8);
        const float4 s1 = *reinterpret_cast<const float4*>(nscale + lane * 8 + 4);
        ushort8 o;
        o[0] = f2bf(v0.x * r * s0.x); o[1] = f2bf(v0.y * r * s0.y);
        o[2] = f2bf(v0.z * r * s0.z); o[3] = f2bf(v0.w * r * s0.w);
        o[4] = f2bf(v1.x * r * s1.x); o[5] = f2bf(v1.y * r * s1.y);
        o[6] = f2bf(v1.z * r * s1.z); o[7] = f2bf(v1.w * r * s1.w);
        *reinterpret_cast<ushort8*>(xnb + (size_t)row * 512 + lane * 8) = o;
    }
}

// ---------------- MFMA GEMM: [8192x512] x [512x512] ----------------
// MODE 0: out bf16, no resid.  MODE 1: out f32 + resid.

template<int MODE>
__global__ __launch_bounds__(256) void kG(
    const unsigned short* __restrict__ A,
    const unsigned short* __restrict__ Bt,
    const float* __restrict__ bias,
    const float* __restrict__ resid,
    void* __restrict__ outp)
{
    __shared__ __align__(16) unsigned short Asm[128 * 64];
    __shared__ __align__(16) unsigned short Bsm[64 * 64];
    const int tid = threadIdx.x;
    const int mt = blockIdx.x >> 3, nt = blockIdx.x & 7;
    const int tok0 = mt * 128, n0 = nt * 64;
    const int w = tid >> 6, lane = tid & 63;
    const int wr = w >> 1, wc = w & 1;
    const int lrow = lane & 15, lk = lane >> 4;

    f32x4 acc[4][2] = {};
    for (int k0 = 0; k0 < 512; k0 += 64) {
        #pragma unroll
        for (int i = 0; i < 4; ++i) {
            const int f = tid + i * 256;          // 0..1023
            const int row = f >> 3, c8 = f & 7;
            const int c8s = c8 ^ (row & 7);       // pre-swizzled source
            gl_lds16(A + (size_t)(tok0 + row) * 512 + k0 + c8s * 8,
                     (char*)Asm + f * 16);
        }
        #pragma unroll
        for (int i = 0; i < 2; ++i) {
            const int f = tid + i * 256;          // 0..511
            const int row = f >> 3, c8 = f & 7;
            const int c8s = c8 ^ (row & 7);
            gl_lds16(Bt + (size_t)(n0 + row) * 512 + k0 + c8s * 8,
                     (char*)Bsm + f * 16);
        }
        __syncthreads();
        #pragma unroll
        for (int kk = 0; kk < 2; ++kk) {
            short8 a[4], b[2];
            #pragma unroll
            for (int m = 0; m < 4; ++m) {
                const int r = wr * 64 + m * 16 + lrow;
                const int byte = (r * 128 + kk * 64 + lk * 16) ^ ((r & 7) << 4);
                a[m] = *reinterpret_cast<const short8*>((const char*)Asm + byte);
            }
            #pragma unroll
            for (int n = 0; n < 2; ++n) {
                const int r = wc * 32 + n * 16 + lrow;
                const int byte = (r * 128 + kk * 64 + lk * 16) ^ ((r & 7) << 4);
                b[n] = *reinterpret_cast<const short8*>((const char*)Bsm + byte);
            }
            #pragma unroll
            for (int m = 0; m < 4; ++m)
                #pragma unroll
                for (int n = 0; n < 2; ++n)
                    acc[m][n] = __builtin_amdgcn_mfma_f32_16x16x32_bf16(
                        a[m], b[n], acc[m][n], 0, 0, 0);
        }
        __syncthreads();
    }
    #pragma unroll
    for (int n = 0; n < 2; ++n) {
        const int ocol = n0 + wc * 32 + n * 16 + lrow;
        const float bs = bias[ocol];
        #pragma unroll
        for (int m = 0; m < 4; ++m) {
            #pragma unroll
            for (int r = 0; r < 4; ++r) {
                const int orow = tok0 + wr * 64 + m * 16 + lk * 4 + r;
                float v = acc[m][n][r] + bs;
                if (MODE == 0) {
                    ((unsigned short*)outp)[(size_t)orow * 512 + ocol] = f2bf(v);
                } else {
                    v += resid[(size_t)orow * 512 + ocol];
                    ((float*)outp)[(size_t)orow * 512 + ocol] = v;
                }
            }
        }
    }
}

// ---------------- attention core ----------------

__global__ __launch_bounds__(256) void k3_attn(
    const float* __restrict__ track, const unsigned short* __restrict__ qwb,
    unsigned short* __restrict__ wtfb)
{
    __shared__ float tf[16][68];
    __shared__ float qwl[8][68];
    __shared__ float lw[8][16];
    const int tid = threadIdx.x;
    const int token = blockIdx.x;
    const int b = token >> 12;
    const int c = token & 4095;
    {
        const int t = tid >> 4;
        const int d4 = (tid & 15) * 4;
        *reinterpret_cast<float4*>(&tf[t][d4]) =
            *reinterpret_cast<const float4*>(track + ((size_t)(b * 16 + t) * 4096 + c) * 64 + d4);
    }
    if (tid < 128) {
        const int h = tid >> 4;
        const int d4 = (tid & 15) * 4;
        const ushort4v q = *reinterpret_cast<const ushort4v*>(qwb + (size_t)token * 512 + h * 64 + d4);
        qwl[h][d4 + 0] = bf2f(q[0]);
        qwl[h][d4 + 1] = bf2f(q[1]);
        qwl[h][d4 + 2] = bf2f(q[2]);
        qwl[h][d4 + 3] = bf2f(q[3]);
    }
    __syncthreads();
    if (tid < 128) {
        const int h = tid >> 4, t = tid & 15;
        float acc = 0.f;
        #pragma unroll
        for (int d = 0; d < 64; ++d) acc += qwl[h][d] * tf[t][d];
        lw[h][t] = acc * 0.125f;
    }
    __syncthreads();
    if (tid < 8) {
        float mx = -1e30f;
        #pragma unroll
        for (int t = 0; t < 16; ++t) mx = fmaxf(mx, lw[tid][t]);
        float ev[16];
        float sum = 0.f;
        #pragma unroll
        for (int t = 0; t < 16; ++t) { ev[t] = expf(lw[tid][t] - mx); sum += ev[t]; }
        const float inv = 1.f / sum;
        #pragma unroll
        for (int t = 0; t < 16; ++t) lw[tid][t] = ev[t] * inv;
    }
    __syncthreads();
    #pragma unroll
    for (int pass = 0; pass < 2; ++pass) {
        const int j = tid + pass * 256;
        const int h = j >> 6, d = j & 63;
        float acc = 0.f;
        #pragma unroll
        for (int t = 0; t < 16; ++t) acc += lw[h][t] * tf[t][d];
        wtfb[(size_t)token * 512 + j] = f2bf(acc);
    }
}

extern "C" void kernel_launch(void* const* d_in, const int* in_sizes, int n_in,
                              void* d_out, int out_size, void* d_ws, size_t ws_size,
                              hipStream_t stream) {
    const float* x      = (const float*)d_in[0];
    const float* track  = (const float*)d_in[1];
    const float* nscale = (const float*)d_in[2];
    const float* wq     = (const float*)d_in[3];
    const float* bq     = (const float*)d_in[4];
    const float* wk     = (const float*)d_in[5];
    // d_in[6] = bk: constant over t per head -> softmax-invariant, omitted exactly
    const float* wv     = (const float*)d_in[7];
    const float* bv     = (const float*)d_in[8];
    const float* wo     = (const float*)d_in[9];
    const float* bo     = (const float*)d_in[10];
    float* buf = (float*)d_out;

    char* ws = (char*)d_ws;
    unsigned short* xnb  = (unsigned short*)ws;                // 8 MB (xn, later wtf)
    unsigned short* qwb  = (unsigned short*)(ws + 8388608);    // 8 MB (qw bf16)
    unsigned short* wqkT = (unsigned short*)(ws + 16777216);   // 512 KB
    unsigned short* wvoT = (unsigned short*)(ws + 17301504);   // 512 KB
    float* bqk = (float*)(ws + 17825792);                      // 2 KB
    float* bvo = (float*)(ws + 17827840);                      // 2 KB

    kprep<<<192 + NTOK / 4, 256, 0, stream>>>(x, nscale, wq, bq, wk, wv, bv, wo, bo,
                                              wqkT, bqk, wvoT, bvo, xnb);
    kG<0><<<512, 256, 0, stream>>>(xnb, wqkT, bqk, nullptr, qwb);
    k3_attn<<<NTOK, 256, 0, stream>>>(track, qwb, xnb);        // xn dead, reuse as wtf
    kG<1><<<512, 256, 0, stream>>>(xnb, wvoT, bvo, x, buf);
}

// Round 4
// 53.818 us; speedup vs baseline: 4.0639x; 1.0920x over previous
//
#include <hip/hip_runtime.h>
#include <math.h>

// TrackCrossAttention, algebraically restructured:
//   wqkT[j=h*64+d][i] = sum_e wq[i][h*64+e]*wk[d][h*64+e]   (bf16, transposed)
//   bqk[h*64+d]       = sum_e bq[h*64+e]*wk[d][h*64+e]
//   wvoT[j][h*64+d]   = sum_e wv[d][h*64+e]*wo[h*64+e][j]   (bf16, transposed)
//   bvo[j]            = sum_e bv[e]*wo[e][j] + bo[j]
// Pipeline (4 kernels):
//   kprep: [bid<64] wqkT/bqk  [64..127] wvoT  [128..191] bvo  [192+] RMSNorm->xn bf16
//   kG<0>: qw = xn @ wqk + bqk -> bf16 (ws)      [MFMA, dbuf prefetch, XCD swizzle]
//   k3   : logits/softmax/wtf -> wtf bf16 (ws)   [2 tok/block, wave-parallel softmax]
//   kG<1>: out = x + wtf @ wvo + bvo -> f32 buf  [MFMA]

#define NTOK 8192

typedef __attribute__((ext_vector_type(8))) short short8;
typedef __attribute__((ext_vector_type(8))) unsigned short ushort8;
typedef __attribute__((ext_vector_type(4))) float f32x4;

__device__ __forceinline__ unsigned short f2bf(float f) {
    unsigned int u = __float_as_uint(f);
    unsigned int r = (u + 0x7fffu + ((u >> 16) & 1u)) >> 16;
    return (unsigned short)r;
}
__device__ __forceinline__ float bf2f(unsigned short s) {
    return __uint_as_float(((unsigned int)s) << 16);
}

__device__ __forceinline__ void gl_lds16(const void* g, void* l) {
    __builtin_amdgcn_global_load_lds(
        (const __attribute__((address_space(1))) unsigned int*)g,
        (__attribute__((address_space(3))) unsigned int*)l,
        16, 0, 0);
}

// ---------------- fused prep: weight folding + RMSNorm ----------------

__global__ __launch_bounds__(256) void kprep(
    const float* __restrict__ x, const float* __restrict__ nscale,
    const float* __restrict__ wq, const float* __restrict__ bq,
    const float* __restrict__ wk, const float* __restrict__ wv,
    const float* __restrict__ bv, const float* __restrict__ wo,
    const float* __restrict__ bo,
    unsigned short* __restrict__ wqkT, float* __restrict__ bqk,
    unsigned short* __restrict__ wvoT, float* __restrict__ bvo,
    unsigned short* __restrict__ xnb)
{
    const int bid = blockIdx.x;
    const int t = threadIdx.x;
    if (bid < 64) {
        __shared__ float wkL[64][65];
        __shared__ float wqL[64][65];
        const int h = bid >> 3;
        const int i0 = (bid & 7) * 64;
        #pragma unroll
        for (int i = 0; i < 16; ++i) {
            const int idx = t + i * 256;
            const int d = idx >> 6, e = idx & 63;
            wkL[d][e] = wk[(size_t)d * 512 + h * 64 + e];
            wqL[d][e] = wq[(size_t)(i0 + d) * 512 + h * 64 + e];
        }
        __syncthreads();
        const int d = t & 63, ig = t >> 6;
        float acc[16];
        #pragma unroll
        for (int ii = 0; ii < 16; ++ii) acc[ii] = 0.f;
        for (int e = 0; e < 64; ++e) {
            const float kv = wkL[d][e];
            #pragma unroll
            for (int ii = 0; ii < 16; ++ii)
                acc[ii] += kv * wqL[ig * 16 + ii][e];
        }
        #pragma unroll
        for (int ii = 0; ii < 16; ++ii)
            wqkT[(size_t)(h * 64 + d) * 512 + i0 + ig * 16 + ii] = f2bf(acc[ii]);
        if (((bid & 7) == 0) && ig == 0) {
            float a = 0.f;
            #pragma unroll
            for (int e = 0; e < 64; ++e) a += bq[h * 64 + e] * wkL[d][e];
            bqk[h * 64 + d] = a;
        }
    } else if (bid < 128) {
        __shared__ float wvL[64][65];
        __shared__ float woL[64][65];
        const int b2 = bid - 64;
        const int h = b2 >> 3;
        const int j0 = (b2 & 7) * 64;
        #pragma unroll
        for (int i = 0; i < 16; ++i) {
            const int idx = t + i * 256;
            const int a = idx >> 6, b = idx & 63;
            wvL[a][b] = wv[(size_t)a * 512 + h * 64 + b];
            woL[a][b] = wo[(size_t)(h * 64 + a) * 512 + j0 + b];
        }
        __syncthreads();
        const int jloc = t & 63, dg = t >> 6;
        float acc[16];
        #pragma unroll
        for (int dd = 0; dd < 16; ++dd) acc[dd] = 0.f;
        for (int e = 0; e < 64; ++e) {
            const float b = woL[e][jloc];
            #pragma unroll
            for (int dd = 0; dd < 16; ++dd)
                acc[dd] += wvL[dg * 16 + dd][e] * b;
        }
        #pragma unroll
        for (int dd = 0; dd < 16; ++dd)
            wvoT[(size_t)(j0 + jloc) * 512 + h * 64 + dg * 16 + dd] = f2bf(acc[dd]);
    } else if (bid < 192) {
        const int b3 = bid - 128;
        const int j = b3 * 8 + (t >> 5);
        const int l = t & 31;
        float p = 0.f;
        #pragma unroll 4
        for (int e = l; e < 512; e += 32) p += bv[e] * wo[(size_t)e * 512 + j];
        #pragma unroll
        for (int m = 1; m < 32; m <<= 1) p += __shfl_xor(p, m, 64);
        if (l == 0) bvo[j] = bo[j] + p;
    } else {
        const int row = (bid - 192) * 4 + (t >> 6);
        const int lane = t & 63;
        const float* xr = x + (size_t)row * 512 + lane * 8;
        const float4 v0 = *reinterpret_cast<const float4*>(xr);
        const float4 v1 = *reinterpret_cast<const float4*>(xr + 4);
        float s = v0.x*v0.x + v0.y*v0.y + v0.z*v0.z + v0.w*v0.w
                + v1.x*v1.x + v1.y*v1.y + v1.z*v1.z + v1.w*v1.w;
        #pragma unroll
        for (int m = 1; m < 64; m <<= 1) s += __shfl_xor(s, m, 64);
        const float r = rsqrtf(s * (1.f / 512.f) + 1e-6f);
        const float4 s0 = *reinterpret_cast<const float4*>(nscale + lane * 8);
        const float4 s1 = *reinterpret_cast<const float4*>(nscale + lane * 8 + 4);
        ushort8 o;
        o[0] = f2bf(v0.x * r * s0.x); o[1] = f2bf(v0.y * r * s0.y);
        o[2] = f2bf(v0.z * r * s0.z); o[3] = f2bf(v0.w * r * s0.w);
        o[4] = f2bf(v1.x * r * s1.x); o[5] = f2bf(v1.y * r * s1.y);
        o[6] = f2bf(v1.z * r * s1.z); o[7] = f2bf(v1.w * r * s1.w);
        *reinterpret_cast<ushort8*>(xnb + (size_t)row * 512 + lane * 8) = o;
    }
}

// ---------------- MFMA GEMM: [8192x512] x [512x512] ----------------
// 128x64 tile, BK=64, double-buffered LDS prefetch, XCD-swizzled grid.
// MODE 0: out bf16, no resid.  MODE 1: out f32 + resid.

template<int MODE>
__global__ __launch_bounds__(256) void kG(
    const unsigned short* __restrict__ A,
    const unsigned short* __restrict__ Bt,
    const float* __restrict__ bias,
    const float* __restrict__ resid,
    void* __restrict__ outp)
{
    __shared__ __align__(16) unsigned short Asm[2][128 * 64];
    __shared__ __align__(16) unsigned short Bsm[2][64 * 64];
    const int tid = threadIdx.x;
    // XCD-aware bijective swizzle: 8 n-blocks of one m-panel -> same XCD L2
    const int hw = blockIdx.x;
    const int logical = (hw & 7) * 64 + (hw >> 3);
    const int mt = logical >> 3, nt = logical & 7;
    const int tok0 = mt * 128, n0 = nt * 64;
    const int w = tid >> 6, lane = tid & 63;
    const int wr = w >> 1, wc = w & 1;
    const int lrow = lane & 15, lk = lane >> 4;

    // per-thread staging indices (rule #21: linear LDS dest, inverse-swizzled src)
    const int srowA[4] = { (tid + 0) >> 3, (tid + 256) >> 3, (tid + 512) >> 3, (tid + 768) >> 3 };
    const int sc8 = tid & 7;

    auto STAGE = [&](int buf, int k0) {
        #pragma unroll
        for (int i = 0; i < 4; ++i) {
            const int f = tid + i * 256;
            const int row = srowA[i];
            const int c8s = sc8 ^ (row & 7);
            gl_lds16(A + (size_t)(tok0 + row) * 512 + k0 + c8s * 8,
                     (char*)&Asm[buf][0] + f * 16);
        }
        #pragma unroll
        for (int i = 0; i < 2; ++i) {
            const int f = tid + i * 256;
            const int row = f >> 3;
            const int c8s = sc8 ^ (row & 7);
            gl_lds16(Bt + (size_t)(n0 + row) * 512 + k0 + c8s * 8,
                     (char*)&Bsm[buf][0] + f * 16);
        }
    };

    f32x4 acc[4][2] = {};
    STAGE(0, 0);
    __syncthreads();
    for (int it = 0; it < 8; ++it) {
        const int cur = it & 1;
        if (it < 7) STAGE(cur ^ 1, (it + 1) * 64);
        #pragma unroll
        for (int kk = 0; kk < 2; ++kk) {
            short8 a[4], b[2];
            #pragma unroll
            for (int m = 0; m < 4; ++m) {
                const int r = wr * 64 + m * 16 + lrow;
                const int byte = (r * 128 + kk * 64 + lk * 16) ^ ((r & 7) << 4);
                a[m] = *reinterpret_cast<const short8*>((const char*)&Asm[cur][0] + byte);
            }
            #pragma unroll
            for (int n = 0; n < 2; ++n) {
                const int r = wc * 32 + n * 16 + lrow;
                const int byte = (r * 128 + kk * 64 + lk * 16) ^ ((r & 7) << 4);
                b[n] = *reinterpret_cast<const short8*>((const char*)&Bsm[cur][0] + byte);
            }
            #pragma unroll
            for (int m = 0; m < 4; ++m)
                #pragma unroll
                for (int n = 0; n < 2; ++n)
                    acc[m][n] = __builtin_amdgcn_mfma_f32_16x16x32_bf16(
                        a[m], b[n], acc[m][n], 0, 0, 0);
        }
        __syncthreads();   // drains vmcnt(0): prefetch issued above has flown under MFMA
    }
    #pragma unroll
    for (int n = 0; n < 2; ++n) {
        const int ocol = n0 + wc * 32 + n * 16 + lrow;
        const float bs = bias[ocol];
        #pragma unroll
        for (int m = 0; m < 4; ++m) {
            #pragma unroll
            for (int r = 0; r < 4; ++r) {
                const int orow = tok0 + wr * 64 + m * 16 + lk * 4 + r;
                float v = acc[m][n][r] + bs;
                if (MODE == 0) {
                    ((unsigned short*)outp)[(size_t)orow * 512 + ocol] = f2bf(v);
                } else {
                    v += resid[(size_t)orow * 512 + ocol];
                    ((float*)outp)[(size_t)orow * 512 + ocol] = v;
                }
            }
        }
    }
}

// ---------------- attention core: 2 tokens/block, parallel softmax ----------------

__global__ __launch_bounds__(256) void k3_attn(
    const float* __restrict__ track, const unsigned short* __restrict__ qwb,
    unsigned short* __restrict__ wtfb)
{
    __shared__ float tf[2][16][68];
    __shared__ float qwl[2][8][68];
    __shared__ float lw[2][8][16];
    const int tid = threadIdx.x;
    const int tok = tid >> 7;         // 0..1
    const int t2 = tid & 127;
    const int token = blockIdx.x * 2 + tok;
    const int b = token >> 12;        // C = 4096
    const int c = token & 4095;
    #pragma unroll
    for (int i = 0; i < 2; ++i) {
        const int f = t2 + i * 128;   // 0..255
        const int row = f >> 4, d4 = (f & 15) * 4;
        *reinterpret_cast<float4*>(&tf[tok][row][d4]) =
            *reinterpret_cast<const float4*>(track + ((size_t)(b * 16 + row) * 4096 + c) * 64 + d4);
    }
    if (t2 < 64) {
        const ushort8 q = *reinterpret_cast<const ushort8*>(qwb + (size_t)token * 512 + t2 * 8);
        #pragma unroll
        for (int j = 0; j < 8; ++j) {
            const int idx = t2 * 8 + j;
            qwl[tok][idx >> 6][idx & 63] = bf2f(q[j]);
        }
    }
    __syncthreads();
    {
        const int h = t2 >> 4, tt = t2 & 15;
        float acc = 0.f;
        #pragma unroll
        for (int d = 0; d < 64; ++d) acc += qwl[tok][h][d] * tf[tok][tt][d];
        float lg = acc * 0.125f;      // 1/sqrt(64)
        float mx = lg;
        #pragma unroll
        for (int m = 1; m < 16; m <<= 1) mx = fmaxf(mx, __shfl_xor(mx, m, 64));
        const float ev = __expf(lg - mx);
        float sum = ev;
        #pragma unroll
        for (int m = 1; m < 16; m <<= 1) sum += __shfl_xor(sum, m, 64);
        lw[tok][h][tt] = ev / sum;
    }
    __syncthreads();
    #pragma unroll
    for (int i = 0; i < 4; ++i) {
        const int j = t2 + i * 128;   // 0..511
        const int h = j >> 6, d = j & 63;
        float acc = 0.f;
        #pragma unroll
        for (int t = 0; t < 16; ++t) acc += lw[tok][h][t] * tf[tok][t][d];
        wtfb[(size_t)token * 512 + j] = f2bf(acc);
    }
}

extern "C" void kernel_launch(void* const* d_in, const int* in_sizes, int n_in,
                              void* d_out, int out_size, void* d_ws, size_t ws_size,
                              hipStream_t stream) {
    const float* x      = (const float*)d_in[0];
    const float* track  = (const float*)d_in[1];
    const float* nscale = (const float*)d_in[2];
    const float* wq     = (const float*)d_in[3];
    const float* bq     = (const float*)d_in[4];
    const float* wk     = (const float*)d_in[5];
    // d_in[6] = bk: constant over t per head -> softmax-invariant, omitted exactly
    const float* wv     = (const float*)d_in[7];
    const float* bv     = (const float*)d_in[8];
    const float* wo     = (const float*)d_in[9];
    const float* bo     = (const float*)d_in[10];
    float* buf = (float*)d_out;

    char* ws = (char*)d_ws;
    unsigned short* xnb  = (unsigned short*)ws;                // 8 MB (xn, later wtf)
    unsigned short* qwb  = (unsigned short*)(ws + 8388608);    // 8 MB (qw bf16)
    unsigned short* wqkT = (unsigned short*)(ws + 16777216);   // 512 KB
    unsigned short* wvoT = (unsigned short*)(ws + 17301504);   // 512 KB
    float* bqk = (float*)(ws + 17825792);                      // 2 KB
    float* bvo = (float*)(ws + 17827840);                      // 2 KB

    kprep<<<192 + NTOK / 4, 256, 0, stream>>>(x, nscale, wq, bq, wk, wv, bv, wo, bo,
                                              wqkT, bqk, wvoT, bvo, xnb);
    kG<0><<<512, 256, 0, stream>>>(xnb, wqkT, bqk, nullptr, qwb);
    k3_attn<<<NTOK / 2, 256, 0, stream>>>(track, qwb, xnb);    // xn dead, reuse as wtf
    kG<1><<<512, 256, 0, stream>>>(xnb, wvoT, bvo, x, buf);
}